// Round 3
// baseline (272.096 us; speedup 1.0000x reference)
//
#include <hip/hip_runtime.h>
#include <hip/hip_cooperative_groups.h>

namespace cg = cooperative_groups;

// TripletAttention on MI355X — single cooperative kernel (3 phases) + fallback.
// y = x * T[b,h,w] with T = 1 + S*cross*g; attention is rank-4
// (maps = mc * (ca, ha, wa)) so QK^T = u^T G u and AV+proj reduce to 3
// weighted exp-sums per row. LN stats from per-pixel sum(x), sum(x^2).

#define B_   32
#define H_   32
#define W_   32
#define C_   256
#define N_   1024           // H_*W_
#define HWC_ (32*32*256)

// ws layout (float offsets)
#define OFF_XW    0          // [B][H][C]  mean over w
#define OFF_XH    262144     // [B][W][C]  mean over h
#define OFF_MC    524288     // [B][N]     mean over c
#define OFF_M2    557056     // [B][N]     sum of x^2 over c
#define OFF_T     589824     // [B][N]
#define OFF_LNP   622592     // [B][16][2] LN partials
#define WS_FLOATS 623616

__device__ __forceinline__ float sigm_(float v){ return 1.f/(1.f + __expf(-v)); }

struct KArgs {
  const float *x;
  const float *cc1_w, *cc1_b, *cc3_dw, *cc3_pw, *cc3_b, *ccd_w, *ccd_b;
  const float *ch1_w, *ch1_b, *ch3_dw, *ch3_pw, *ch3_b, *chd_w, *chd_b;
  const float *cw1_w, *cw1_b, *cw3_dw, *cw3_pw, *cw3_b, *cwd_w, *cwd_b;
  const float *branch_w, *d1_w, *d1_b, *d2_w, *d2_b;
  const float *q_w, *q_b, *k_w, *k_b, *v_w, *v_b, *o_w, *o_b;
  const float *gamma, *beta;
  float *ws; float *out;
};

// ---------------- branch evaluator over a [32][C] LDS profile
__device__ __forceinline__ void branch_1d(const float* __restrict__ Xs, float* __restrict__ outg,
    const float* __restrict__ w1, const float* __restrict__ b1,
    const float* __restrict__ dw, const float* __restrict__ pw, const float* __restrict__ b3,
    const float* __restrict__ wd, const float* __restrict__ bd, int lane, int wave)
{
  for (int i = 0; i < 8; ++i){
    const int h = wave*8 + i;
    float s1 = 0.f, s3 = 0.f, sd = 0.f;
    #pragma unroll
    for (int k = 0; k < 4; ++k){
      const int c = lane + k*64;
      const float x0  = Xs[h*C_ + c];
      const float xm1 = (h > 0)  ? Xs[(h-1)*C_ + c] : 0.f;
      const float xp1 = (h < 31) ? Xs[(h+1)*C_ + c] : 0.f;
      const float xm2 = (h > 1)  ? Xs[(h-2)*C_ + c] : 0.f;
      const float xp2 = (h < 30) ? Xs[(h+2)*C_ + c] : 0.f;
      s1 = fmaf(x0, w1[c], s1);
      const float dv = xm1*dw[3*C_+c] + x0*dw[4*C_+c] + xp1*dw[5*C_+c];
      s3 = fmaf(dv, pw[c], s3);
      sd += xm2*wd[3*C_+c] + x0*wd[4*C_+c] + xp2*wd[5*C_+c];
    }
    #pragma unroll
    for (int d = 1; d < 64; d <<= 1){ s1 += __shfl_xor(s1,d); s3 += __shfl_xor(s3,d); sd += __shfl_xor(sd,d); }
    if (lane == 0)
      outg[h] = (sigm_(s1 + b1[0]) + sigm_(s3 + b3[0]) + sigm_(sd + bd[0])) * (1.f/3.f);
  }
}

#define ATT1(MV, WV) do{                       \
    const float vv = fmaf(p2, (WV), th);       \
    const float ss = fmaf((MV), vv, p3);       \
    const float ee = exp2f(ss);                \
    Z += ee;                                   \
    const float em = ee * (MV);                \
    semc += em;                                \
    A2 = fmaf(em, (WV), A2);                   \
  }while(0)

// ================= fused cooperative kernel: 512 blocks x 256 =================
__global__ __launch_bounds__(256, 2) void fused(KArgs A){
  cg::grid_group grid = cg::this_grid();
  __shared__ __align__(16) float Xs [H_*C_];      // phase2: xw[b]
  __shared__ __align__(16) float Xs2[H_*C_];      // phase2: xh[b]
  __shared__ __align__(16) float mcs[2*1032];     // phase2: 2 copies of mc[b]; phase1 scratch
  __shared__ float gvec[C_];
  __shared__ float ha_s[32], wa_s[32], cst[24], sc[2], red[8];
  __shared__ float a1s[2][32];
  __shared__ float mu_r[2];

  const int bid = blockIdx.x;
  const int tid = threadIdx.x, lane = tid & 63, wv = tid >> 6;
  float* ws = A.ws;
  float4* sl4 = (float4*)mcs;   // phase-1 overlay (<= 4 KB)

  // ================= Phase 1: reductions =================
  // two slab tasks: s = 2*bid+t -> (b,h): mc,m2 rows + xw row
  #pragma unroll
  for (int t = 0; t < 2; ++t){
    const int s = (bid<<1) | t, b = s >> 5, h = s & 31;
    const float* xp = A.x + (size_t)s*(W_*C_);
    float4 v[8];
    #pragma unroll
    for (int k = 0; k < 8; ++k) v[k] = ((const float4*)xp)[tid + k*256];
    #pragma unroll
    for (int k = 0; k < 8; ++k){
      float sm = v[k].x + v[k].y + v[k].z + v[k].w;
      float q  = v[k].x*v[k].x + v[k].y*v[k].y + v[k].z*v[k].z + v[k].w*v[k].w;
      #pragma unroll
      for (int d = 1; d < 64; d <<= 1){ sm += __shfl_xor(sm, d); q += __shfl_xor(q, d); }
      if (lane == 0){
        const int w = k*4 + wv;
        ws[OFF_MC + b*N_ + h*W_ + w] = sm * (1.f/C_);
        ws[OFF_M2 + b*N_ + h*W_ + w] = q;
      }
    }
    float4 acc = v[0];
    #pragma unroll
    for (int k = 1; k < 8; ++k){ acc.x += v[k].x; acc.y += v[k].y; acc.z += v[k].z; acc.w += v[k].w; }
    __syncthreads();
    sl4[tid] = acc;
    __syncthreads();
    if (tid < 64){
      const float4 p0 = sl4[tid], p1 = sl4[tid+64], p2 = sl4[tid+128], p3 = sl4[tid+192];
      float4 o;
      o.x = (p0.x+p1.x+p2.x+p3.x)*(1.f/W_);
      o.y = (p0.y+p1.y+p2.y+p3.y)*(1.f/W_);
      o.z = (p0.z+p1.z+p2.z+p3.z)*(1.f/W_);
      o.w = (p0.w+p1.w+p2.w+p3.w)*(1.f/W_);
      ((float4*)(ws + OFF_XW + (b*H_ + h)*C_))[tid] = o;
    }
  }
  // two column tasks: u = 2*bid+t -> (b,w): xh column
  #pragma unroll
  for (int t = 0; t < 2; ++t){
    const int u = (bid<<1) | t, b = u >> 5, w = u & 31;
    const int hh = tid >> 6, c4 = (tid & 63)*4;
    const float* xp = A.x + (size_t)b*HWC_ + (size_t)w*C_ + c4;
    float4 acc = {0.f,0.f,0.f,0.f};
    #pragma unroll
    for (int hb = 0; hb < 8; ++hb){
      const int h = hb*4 + hh;
      const float4 v = *(const float4*)(xp + (size_t)h*(W_*C_));
      acc.x += v.x; acc.y += v.y; acc.z += v.z; acc.w += v.w;
    }
    __syncthreads();
    sl4[tid] = acc;
    __syncthreads();
    if (tid < 64){
      const float4 a = sl4[tid], b2 = sl4[tid+64], c = sl4[tid+128], d = sl4[tid+192];
      float4 o;
      o.x = (a.x+b2.x+c.x+d.x)*(1.f/H_);
      o.y = (a.y+b2.y+c.y+d.y)*(1.f/H_);
      o.z = (a.z+b2.z+c.z+d.z)*(1.f/H_);
      o.w = (a.w+b2.w+c.w+d.w)*(1.f/H_);
      *(float4*)&ws[OFF_XH + (b*W_ + w)*C_ + tid*4] = o;
    }
  }
  __threadfence();
  grid.sync();

  // ================= Phase 2: gates + rank-4 attention =================
  const int b = bid >> 4, rblk = bid & 15;
  { const float4* s1 = (const float4*)(ws + OFF_XW + b*(H_*C_));
    const float4* s2 = (const float4*)(ws + OFF_XH + b*(W_*C_));
    #pragma unroll
    for (int k = 0; k < 8; ++k){
      ((float4*)Xs )[tid + k*256] = s1[tid + k*256];
      ((float4*)Xs2)[tid + k*256] = s2[tid + k*256];
    }
    const float4 v = ((const float4*)(ws + OFF_MC + b*N_))[tid];
    *(float4*)&mcs[tid*4]        = v;
    *(float4*)&mcs[1032 + tid*4] = v;
  }
  __syncthreads();

  { float s = 0.f;
    #pragma unroll
    for (int h = 0; h < H_; ++h) s += Xs[h*C_ + tid];
    gvec[tid] = s * (1.f/H_); }

  branch_1d(Xs,  ha_s, A.ch1_w, A.ch1_b, A.ch3_dw, A.ch3_pw, A.ch3_b, A.chd_w, A.chd_b, lane, wv);
  branch_1d(Xs2, wa_s, A.cw1_w, A.cw1_b, A.cw3_dw, A.cw3_pw, A.cw3_b, A.cwd_w, A.cwd_b, lane, wv);
  __syncthreads();

  if (wv == 0){
    float s1 = 0.f, s3 = 0.f, sd = 0.f;
    #pragma unroll
    for (int k = 0; k < 4; ++k){
      const int c = lane + k*64;
      const float v = gvec[c];
      s1 = fmaf(v, A.cc1_w[c], s1);
      s3 = fmaf(v*A.cc3_dw[4*C_+c], A.cc3_pw[c], s3);
      sd = fmaf(v, A.ccd_w[4*C_+c], sd);
    }
    #pragma unroll
    for (int d = 1; d < 64; d <<= 1){ s1 += __shfl_xor(s1,d); s3 += __shfl_xor(s3,d); sd += __shfl_xor(sd,d); }
    if (lane == 0)
      sc[0] = (sigm_(s1+A.cc1_b[0]) + sigm_(s3+A.cc3_b[0]) + sigm_(sd+A.ccd_b[0])) * (1.f/3.f);
  } else if (wv == 1){
    float acc = 0.f;
    for (int r = 0; r < 16; ++r){
      float s = 0.f;
      #pragma unroll
      for (int k = 0; k < 4; ++k){ const int c = lane + k*64; s = fmaf(gvec[c], A.d1_w[c*16 + r], s); }
      #pragma unroll
      for (int d = 1; d < 64; d <<= 1) s += __shfl_xor(s, d);
      acc = fmaf(fmaxf(s + A.d1_b[r], 0.f), A.d2_w[r], acc);
    }
    if (lane == 0) sc[1] = sigm_(acc + A.d2_b[0]);
  } else if (wv == 2){
    if (lane < 16){
      const int i = lane >> 2, j = lane & 3;
      float s = 0.f;
      #pragma unroll
      for (int d = 0; d < 8; ++d){
        const float qv = (i < 3) ? A.q_w[i*8+d] : A.q_b[d];
        const float kv = (j < 3) ? A.k_w[j*8+d] : A.k_b[d];
        s = fmaf(qv, kv, s);
      }
      cst[i*4 + j] = s * 0.51010305898f;   // log2(e)/sqrt(8)
    } else if (lane < 19){
      const int i = lane - 16;
      float s = 0.f;
      #pragma unroll
      for (int d = 0; d < 8; ++d) s = fmaf(A.v_w[i*8+d], A.o_w[d], s);
      cst[lane] = s;
    } else if (lane == 19){
      float s = A.o_b[0];
      #pragma unroll
      for (int d = 0; d < 8; ++d) s = fmaf(A.v_b[d], A.o_w[d], s);
      cst[19] = s;
    } else if (lane == 20){
      const float b0 = A.branch_w[0], b1 = A.branch_w[1], b2 = A.branch_w[2];
      const float mx = fmaxf(b0, fmaxf(b1, b2));
      const float e0 = __expf(b0-mx), e1 = __expf(b1-mx), e2 = __expf(b2-mx);
      const float inv = 1.f/(e0+e1+e2);
      cst[20] = e0*inv; cst[21] = e1*inv; cst[22] = e2*inv;
    }
  }
  __syncthreads();

  const float ca = sc[0], gg = sc[1];
  const int r = tid >> 2, sub = tid & 3;
  const int n = rblk*64 + r;
  const int hn = n >> 5, wn = n & 31;
  const float mcn = mcs[n];
  const float u0 = mcn*ca, u1 = mcn*ha_s[hn], u2 = mcn*wa_s[wn];
  const float p0 = u0*cst[0] + u1*cst[4] + u2*cst[8]  + cst[12];
  const float p1 = u0*cst[1] + u1*cst[5] + u2*cst[9]  + cst[13];
  const float p2 = u0*cst[2] + u1*cst[6] + u2*cst[10] + cst[14];
  const float p3 = u0*cst[3] + u1*cst[7] + u2*cst[11] + cst[15];
  const float pc = p0 * ca;

  float Z = 0.f, A0 = 0.f, A1 = 0.f, A2 = 0.f;
  const float* mrow_base = &mcs[(sub & 1)*1032];
  for (int i = 0; i < 8; ++i){
    const int hm = sub*8 + i;
    const float th = fmaf(p1, ha_s[hm], pc);
    float semc = 0.f;
    const float* mrow = mrow_base + hm*32;
    #pragma unroll
    for (int wm = 0; wm < 32; wm += 4){
      const float4 m4 = *(const float4*)&mrow[wm];
      const float4 w4 = *(const float4*)&wa_s[wm];
      ATT1(m4.x, w4.x);
      ATT1(m4.y, w4.y);
      ATT1(m4.z, w4.z);
      ATT1(m4.w, w4.w);
    }
    A0 += semc; A1 = fmaf(ha_s[hm], semc, A1);
  }
  Z  += __shfl_xor(Z,1);  Z  += __shfl_xor(Z,2);
  A0 += __shfl_xor(A0,1); A0 += __shfl_xor(A0,2);
  A1 += __shfl_xor(A1,1); A1 += __shfl_xor(A1,2);
  A2 += __shfl_xor(A2,1); A2 += __shfl_xor(A2,2);

  float t1 = 0.f, t2 = 0.f;
  if (sub == 0){
    const float invZ = 1.f / Z;
    const float dot = (ca*cst[16]*A0 + cst[17]*A1 + cst[18]*A2) * invZ + cst[19];
    const float cross = 1.f / (1.f + __expf(-dot));
    const float S = cst[20]*ca + cst[21]*ha_s[hn] + cst[22]*wa_s[wn];
    const float T = fmaf(S*cross, gg, 1.f);
    ws[OFF_T + b*N_ + n] = T;
    t1 = T * mcn * (float)C_;
    t2 = T * T * ws[OFF_M2 + b*N_ + n];
  }
  #pragma unroll
  for (int d = 1; d < 64; d <<= 1){ t1 += __shfl_xor(t1,d); t2 += __shfl_xor(t2,d); }
  if (lane == 0){ red[wv] = t1; red[4+wv] = t2; }
  __syncthreads();
  if (tid == 0){
    ws[OFF_LNP + (b*16 + rblk)*2 + 0] = red[0]+red[1]+red[2]+red[3];
    ws[OFF_LNP + (b*16 + rblk)*2 + 1] = red[4]+red[5]+red[6]+red[7];
  }
  __threadfence();
  grid.sync();

  // ================= Phase 3: LN finalize + elementwise =================
  if (tid == 0){
    float s1 = 0.f, s2 = 0.f;
    for (int i = 0; i < 16; ++i){
      s1 += ws[OFF_LNP + (b*16+i)*2 + 0];
      s2 += ws[OFF_LNP + (b*16+i)*2 + 1];
    }
    const float mu  = s1 * (1.f/HWC_);
    const float var = s2 * (1.f/HWC_) - mu*mu;
    const float rstd = rsqrtf(var + 1e-3f);
    mu_r[0] = mu * rstd; mu_r[1] = rstd;
  }
  __syncthreads();
  if (tid < 64){
    const int t = tid >> 5, wq = tid & 31;
    const int h = ((bid<<1) | t) & 31;
    a1s[t][wq] = ws[OFF_T + b*N_ + h*32 + wq] * mu_r[1];
  }
  __syncthreads();
  const float murstd = mu_r[0];
  #pragma unroll
  for (int t = 0; t < 2; ++t){
    const int s = (bid<<1) | t, h = s & 31;
    const size_t base = (size_t)s*(W_*C_);
    const float4* xp = (const float4*)(A.x + base);
    const float4* gp = (const float4*)(A.gamma + (size_t)h*(W_*C_));
    const float4* bp = (const float4*)(A.beta  + (size_t)h*(W_*C_));
    float4* op = (float4*)(A.out + base);
    #pragma unroll
    for (int k = 0; k < 8; ++k){
      const int f = tid + k*256;
      const float a1 = a1s[t][f >> 6];
      const float4 xv = xp[f], gv = gp[f], bv = bp[f];
      float4 o;
      o.x = fmaf(fmaf(xv.x, a1, -murstd), gv.x, bv.x);
      o.y = fmaf(fmaf(xv.y, a1, -murstd), gv.y, bv.y);
      o.z = fmaf(fmaf(xv.z, a1, -murstd), gv.z, bv.z);
      o.w = fmaf(fmaf(xv.w, a1, -murstd), gv.w, bv.w);
      op[f] = o;
    }
  }
}

// ================= fallback kernels (round-2 proven path) =================
__global__ __launch_bounds__(256) void kAB(const float* __restrict__ x, float* __restrict__ ws){
  const int blk = blockIdx.x;
  const int tid = threadIdx.x, lane = tid & 63, wv = tid >> 6;
  if (blk < 1024){
    const int b = blk >> 5, h = blk & 31;
    const float* xp = x + (size_t)(b*H_ + h)*(W_*C_);
    float4 v[8];
    #pragma unroll
    for (int k = 0; k < 8; ++k) v[k] = ((const float4*)xp)[tid + k*256];
    #pragma unroll
    for (int k = 0; k < 8; ++k){
      float s = v[k].x + v[k].y + v[k].z + v[k].w;
      float q = v[k].x*v[k].x + v[k].y*v[k].y + v[k].z*v[k].z + v[k].w*v[k].w;
      #pragma unroll
      for (int d = 1; d < 64; d <<= 1){ s += __shfl_xor(s, d); q += __shfl_xor(q, d); }
      if (lane == 0){
        const int w = k*4 + wv;
        ws[OFF_MC + b*N_ + h*W_ + w] = s * (1.f/C_);
        ws[OFF_M2 + b*N_ + h*W_ + w] = q;
      }
    }
    float4 a = v[0];
    #pragma unroll
    for (int k = 1; k < 8; ++k){ a.x += v[k].x; a.y += v[k].y; a.z += v[k].z; a.w += v[k].w; }
    __shared__ float4 cs[256];
    cs[tid] = a;
    __syncthreads();
    if (tid < 64){
      const float4 p0 = cs[tid], p1 = cs[tid+64], p2 = cs[tid+128], p3 = cs[tid+192];
      float4 o;
      o.x = (p0.x+p1.x+p2.x+p3.x)*(1.f/W_);
      o.y = (p0.y+p1.y+p2.y+p3.y)*(1.f/W_);
      o.z = (p0.z+p1.z+p2.z+p3.z)*(1.f/W_);
      o.w = (p0.w+p1.w+p2.w+p3.w)*(1.f/W_);
      ((float4*)(ws + OFF_XW + (b*H_ + h)*C_))[tid] = o;
    }
  } else {
    const int blk2 = blk - 1024, b = blk2 >> 5, w = blk2 & 31;
    __shared__ float4 sl4[256];
    const int hh = tid >> 6, c4 = (tid & 63)*4;
    const float* xp = x + (size_t)b*HWC_ + (size_t)w*C_ + c4;
    float4 acc = {0.f,0.f,0.f,0.f};
    #pragma unroll
    for (int hb = 0; hb < 8; ++hb){
      const int h = hb*4 + hh;
      const float4 v = *(const float4*)(xp + (size_t)h*(W_*C_));
      acc.x += v.x; acc.y += v.y; acc.z += v.z; acc.w += v.w;
    }
    sl4[tid] = acc;
    __syncthreads();
    if (tid < 64){
      const float4 a = sl4[tid], b2 = sl4[tid+64], c = sl4[tid+128], d = sl4[tid+192];
      float4 o;
      o.x = (a.x+b2.x+c.x+d.x)*(1.f/H_);
      o.y = (a.y+b2.y+c.y+d.y)*(1.f/H_);
      o.z = (a.z+b2.z+c.z+d.z)*(1.f/H_);
      o.w = (a.w+b2.w+c.w+d.w)*(1.f/H_);
      *(float4*)&ws[OFF_XH + (b*W_ + w)*C_ + tid*4] = o;
    }
  }
}

__global__ __launch_bounds__(256) void kCD(KArgs A){
  __shared__ __align__(16) float Xs [H_*C_];
  __shared__ __align__(16) float Xs2[H_*C_];
  __shared__ __align__(16) float mcs[2*1032];
  __shared__ float gvec[C_];
  __shared__ float ha_s[32], wa_s[32], cst[24], sc[2], red[8];
  float* ws = A.ws;
  const int blk = blockIdx.x, b = blk >> 4, rblk = blk & 15;
  const int tid = threadIdx.x, lane = tid & 63, wv = tid >> 6;

  { const float4* s1 = (const float4*)(ws + OFF_XW + b*(H_*C_));
    const float4* s2 = (const float4*)(ws + OFF_XH + b*(W_*C_));
    #pragma unroll
    for (int k = 0; k < 8; ++k){
      ((float4*)Xs )[tid + k*256] = s1[tid + k*256];
      ((float4*)Xs2)[tid + k*256] = s2[tid + k*256];
    }
    const float4 v = ((const float4*)(ws + OFF_MC + b*N_))[tid];
    *(float4*)&mcs[tid*4]        = v;
    *(float4*)&mcs[1032 + tid*4] = v;
  }
  __syncthreads();
  { float s = 0.f;
    #pragma unroll
    for (int h = 0; h < H_; ++h) s += Xs[h*C_ + tid];
    gvec[tid] = s * (1.f/H_); }
  branch_1d(Xs,  ha_s, A.ch1_w, A.ch1_b, A.ch3_dw, A.ch3_pw, A.ch3_b, A.chd_w, A.chd_b, lane, wv);
  branch_1d(Xs2, wa_s, A.cw1_w, A.cw1_b, A.cw3_dw, A.cw3_pw, A.cw3_b, A.cwd_w, A.cwd_b, lane, wv);
  __syncthreads();
  if (wv == 0){
    float s1 = 0.f, s3 = 0.f, sd = 0.f;
    #pragma unroll
    for (int k = 0; k < 4; ++k){
      const int c = lane + k*64;
      const float v = gvec[c];
      s1 = fmaf(v, A.cc1_w[c], s1);
      s3 = fmaf(v*A.cc3_dw[4*C_+c], A.cc3_pw[c], s3);
      sd = fmaf(v, A.ccd_w[4*C_+c], sd);
    }
    #pragma unroll
    for (int d = 1; d < 64; d <<= 1){ s1 += __shfl_xor(s1,d); s3 += __shfl_xor(s3,d); sd += __shfl_xor(sd,d); }
    if (lane == 0)
      sc[0] = (sigm_(s1+A.cc1_b[0]) + sigm_(s3+A.cc3_b[0]) + sigm_(sd+A.ccd_b[0])) * (1.f/3.f);
  } else if (wv == 1){
    float acc = 0.f;
    for (int r = 0; r < 16; ++r){
      float s = 0.f;
      #pragma unroll
      for (int k = 0; k < 4; ++k){ const int c = lane + k*64; s = fmaf(gvec[c], A.d1_w[c*16 + r], s); }
      #pragma unroll
      for (int d = 1; d < 64; d <<= 1) s += __shfl_xor(s, d);
      acc = fmaf(fmaxf(s + A.d1_b[r], 0.f), A.d2_w[r], acc);
    }
    if (lane == 0) sc[1] = sigm_(acc + A.d2_b[0]);
  } else if (wv == 2){
    if (lane < 16){
      const int i = lane >> 2, j = lane & 3;
      float s = 0.f;
      #pragma unroll
      for (int d = 0; d < 8; ++d){
        const float qv = (i < 3) ? A.q_w[i*8+d] : A.q_b[d];
        const float kv = (j < 3) ? A.k_w[j*8+d] : A.k_b[d];
        s = fmaf(qv, kv, s);
      }
      cst[i*4 + j] = s * 0.51010305898f;
    } else if (lane < 19){
      const int i = lane - 16;
      float s = 0.f;
      #pragma unroll
      for (int d = 0; d < 8; ++d) s = fmaf(A.v_w[i*8+d], A.o_w[d], s);
      cst[lane] = s;
    } else if (lane == 19){
      float s = A.o_b[0];
      #pragma unroll
      for (int d = 0; d < 8; ++d) s = fmaf(A.v_b[d], A.o_w[d], s);
      cst[19] = s;
    } else if (lane == 20){
      const float b0 = A.branch_w[0], b1 = A.branch_w[1], b2 = A.branch_w[2];
      const float mx = fmaxf(b0, fmaxf(b1, b2));
      const float e0 = __expf(b0-mx), e1 = __expf(b1-mx), e2 = __expf(b2-mx);
      const float inv = 1.f/(e0+e1+e2);
      cst[20] = e0*inv; cst[21] = e1*inv; cst[22] = e2*inv;
    }
  }
  __syncthreads();
  const float ca = sc[0], gg = sc[1];
  const int r = tid >> 2, sub = tid & 3;
  const int n = rblk*64 + r;
  const int hn = n >> 5, wn = n & 31;
  const float mcn = mcs[n];
  const float u0 = mcn*ca, u1 = mcn*ha_s[hn], u2 = mcn*wa_s[wn];
  const float p0 = u0*cst[0] + u1*cst[4] + u2*cst[8]  + cst[12];
  const float p1 = u0*cst[1] + u1*cst[5] + u2*cst[9]  + cst[13];
  const float p2 = u0*cst[2] + u1*cst[6] + u2*cst[10] + cst[14];
  const float p3 = u0*cst[3] + u1*cst[7] + u2*cst[11] + cst[15];
  const float pc = p0 * ca;
  float Z = 0.f, A0 = 0.f, A1 = 0.f, A2 = 0.f;
  const float* mrow_base = &mcs[(sub & 1)*1032];
  for (int i = 0; i < 8; ++i){
    const int hm = sub*8 + i;
    const float th = fmaf(p1, ha_s[hm], pc);
    float semc = 0.f;
    const float* mrow = mrow_base + hm*32;
    #pragma unroll
    for (int wm = 0; wm < 32; wm += 4){
      const float4 m4 = *(const float4*)&mrow[wm];
      const float4 w4 = *(const float4*)&wa_s[wm];
      ATT1(m4.x, w4.x);
      ATT1(m4.y, w4.y);
      ATT1(m4.z, w4.z);
      ATT1(m4.w, w4.w);
    }
    A0 += semc; A1 = fmaf(ha_s[hm], semc, A1);
  }
  Z  += __shfl_xor(Z,1);  Z  += __shfl_xor(Z,2);
  A0 += __shfl_xor(A0,1); A0 += __shfl_xor(A0,2);
  A1 += __shfl_xor(A1,1); A1 += __shfl_xor(A1,2);
  A2 += __shfl_xor(A2,1); A2 += __shfl_xor(A2,2);
  float t1 = 0.f, t2 = 0.f;
  if (sub == 0){
    const float invZ = 1.f / Z;
    const float dot = (ca*cst[16]*A0 + cst[17]*A1 + cst[18]*A2) * invZ + cst[19];
    const float cross = 1.f / (1.f + __expf(-dot));
    const float S = cst[20]*ca + cst[21]*ha_s[hn] + cst[22]*wa_s[wn];
    const float T = fmaf(S*cross, gg, 1.f);
    ws[OFF_T + b*N_ + n] = T;
    t1 = T * mcn * (float)C_;
    t2 = T * T * ws[OFF_M2 + b*N_ + n];
  }
  #pragma unroll
  for (int d = 1; d < 64; d <<= 1){ t1 += __shfl_xor(t1,d); t2 += __shfl_xor(t2,d); }
  if (lane == 0){ red[wv] = t1; red[4+wv] = t2; }
  __syncthreads();
  if (tid == 0){
    ws[OFF_LNP + (b*16 + rblk)*2 + 0] = red[0]+red[1]+red[2]+red[3];
    ws[OFF_LNP + (b*16 + rblk)*2 + 1] = red[4]+red[5]+red[6]+red[7];
  }
}

__global__ __launch_bounds__(256) void kF(const float* __restrict__ x, const float* __restrict__ gamma,
                                          const float* __restrict__ beta, const float* __restrict__ ws,
                                          float* __restrict__ out){
  const int blk = blockIdx.x, b = blk >> 5, h = blk & 31;
  const int tid = threadIdx.x;
  __shared__ float a1s[32];
  __shared__ float mu_r[2];
  if (tid == 0){
    float s1 = 0.f, s2 = 0.f;
    for (int i = 0; i < 16; ++i){
      s1 += ws[OFF_LNP + (b*16+i)*2 + 0];
      s2 += ws[OFF_LNP + (b*16+i)*2 + 1];
    }
    const float mu  = s1 * (1.f/HWC_);
    const float var = s2 * (1.f/HWC_) - mu*mu;
    const float rstd = rsqrtf(var + 1e-3f);
    mu_r[0] = mu * rstd; mu_r[1] = rstd;
  }
  __syncthreads();
  if (tid < 32) a1s[tid] = ws[OFF_T + b*N_ + h*32 + tid] * mu_r[1];
  __syncthreads();
  const float murstd = mu_r[0];
  const size_t base = (size_t)(b*H_ + h)*(W_*C_);
  const float4* xp = (const float4*)(x + base);
  const float4* gp = (const float4*)(gamma + (size_t)h*(W_*C_));
  const float4* bp = (const float4*)(beta  + (size_t)h*(W_*C_));
  float4* op = (float4*)(out + base);
  #pragma unroll
  for (int k = 0; k < 8; ++k){
    const int f = tid + k*256;
    const float a1 = a1s[f >> 6];
    const float4 xv = xp[f], gv = gp[f], bv = bp[f];
    float4 o;
    o.x = fmaf(fmaf(xv.x, a1, -murstd), gv.x, bv.x);
    o.y = fmaf(fmaf(xv.y, a1, -murstd), gv.y, bv.y);
    o.z = fmaf(fmaf(xv.z, a1, -murstd), gv.z, bv.z);
    o.w = fmaf(fmaf(xv.w, a1, -murstd), gv.w, bv.w);
    op[f] = o;
  }
}

extern "C" void kernel_launch(void* const* d_in, const int* in_sizes, int n_in,
                              void* d_out, int out_size, void* d_ws, size_t ws_size,
                              hipStream_t stream){
  (void)in_sizes; (void)n_in; (void)out_size;
  if (ws_size < (size_t)WS_FLOATS * sizeof(float)) return;
  KArgs ka;
  ka.x      = (const float*)d_in[0];
  ka.cc1_w  = (const float*)d_in[1];  ka.cc1_b  = (const float*)d_in[2];
  ka.cc3_dw = (const float*)d_in[3];  ka.cc3_pw = (const float*)d_in[4];
  ka.cc3_b  = (const float*)d_in[5];  ka.ccd_w  = (const float*)d_in[6];
  ka.ccd_b  = (const float*)d_in[7];
  ka.ch1_w  = (const float*)d_in[8];  ka.ch1_b  = (const float*)d_in[9];
  ka.ch3_dw = (const float*)d_in[10]; ka.ch3_pw = (const float*)d_in[11];
  ka.ch3_b  = (const float*)d_in[12]; ka.chd_w  = (const float*)d_in[13];
  ka.chd_b  = (const float*)d_in[14];
  ka.cw1_w  = (const float*)d_in[15]; ka.cw1_b  = (const float*)d_in[16];
  ka.cw3_dw = (const float*)d_in[17]; ka.cw3_pw = (const float*)d_in[18];
  ka.cw3_b  = (const float*)d_in[19]; ka.cwd_w  = (const float*)d_in[20];
  ka.cwd_b  = (const float*)d_in[21];
  ka.branch_w = (const float*)d_in[22];
  ka.d1_w   = (const float*)d_in[23]; ka.d1_b   = (const float*)d_in[24];
  ka.d2_w   = (const float*)d_in[25]; ka.d2_b   = (const float*)d_in[26];
  ka.q_w    = (const float*)d_in[27]; ka.q_b    = (const float*)d_in[28];
  ka.k_w    = (const float*)d_in[29]; ka.k_b    = (const float*)d_in[30];
  ka.v_w    = (const float*)d_in[31]; ka.v_b    = (const float*)d_in[32];
  ka.o_w    = (const float*)d_in[33]; ka.o_b    = (const float*)d_in[34];
  ka.gamma  = (const float*)d_in[35]; ka.beta   = (const float*)d_in[36];
  ka.ws = (float*)d_ws;
  ka.out = (float*)d_out;

  void* kp[1] = { (void*)&ka };
  hipError_t e = hipLaunchCooperativeKernel((void*)fused, dim3(512), dim3(256), kp, 0, stream);
  if (e != hipSuccess){
    (void)hipGetLastError();
    kAB<<<dim3(2048), dim3(256), 0, stream>>>(ka.x, ka.ws);
    kCD<<<dim3(B_*16), dim3(256), 0, stream>>>(ka);
    kF<<<dim3(B_*H_), dim3(256), 0, stream>>>(ka.x, ka.gamma, ka.beta, ka.ws, (float*)d_out);
  }
}